// Round 1
// baseline (1086.563 us; speedup 1.0000x reference)
//
#include <hip/hip_runtime.h>
#include <hip/hip_fp16.h>
#include <stdint.h>

typedef _Float16 f16;
typedef _Float16 f16x8 __attribute__((ext_vector_type(8)));
typedef _Float16 f16x4 __attribute__((ext_vector_type(4)));
typedef float f32x4 __attribute__((ext_vector_type(4)));

#define NB 256
#define NT 256
#define ND 300
#define NH 200
#define NOUT 100
#define C3H 600
#define NTILE 40         // 640 padded cols = 40 tiles of 16
#define NKCX 10          // K=300 -> 320 = 10 chunks of 32
#define NKCH 7           // K=200 -> 224 = 7 chunks of 32
#define XPC 608          // xp stored cols (38 real tiles)

#define XP_BYTES   (2ull * NT * NB * XPC * 2)        // 159,383,552
#define WXP_BYTES  (2ull * NKCX * NTILE * 512 * 2)   // 819,200
#define WHP_BYTES  (2ull * NKCH * NTILE * 512 * 2)   // 573,440

typedef const __attribute__((address_space(1))) uint32_t ga_u32;
typedef __attribute__((address_space(3))) uint32_t lds_u32;

__device__ __forceinline__ float sigm(float x) {
  x = fminf(fmaxf(x, -60.f), 60.f);
  return 1.f / (1.f + __expf(-x));
}
__device__ __forceinline__ float tanh_f(float x) {
  x = fminf(fmaxf(x, -15.f), 15.f);
  float e = __expf(2.f * x);
  return (e - 1.f) / (e + 1.f);
}

// ---------------------------------------------------------------------------
// Pack Wx/Wh (fp32 [K][600]) into f16 per-lane MFMA B-fragment streams:
// [dir][kc][tile][lane][j]: element = W[k][col], k = kc*32+(lane>>4)*8+j,
// col = tile*16+(lane&15); zero-padded for k/col out of range.
// ---------------------------------------------------------------------------
__global__ void pack_w(const float* __restrict__ Wxf, const float* __restrict__ Wxb,
                       const float* __restrict__ Whf, const float* __restrict__ Whb,
                       f16* __restrict__ wxp, f16* __restrict__ whp) {
  int e = blockIdx.x * 256 + threadIdx.x;
  const int NX = 2 * NKCX * NTILE * 512;
  const int NHW = 2 * NKCH * NTILE * 512;
  if (e < NX) {
    int j = e & 7, lane = (e >> 3) & 63;
    int tile = (e >> 9) % NTILE;
    int kc = ((e >> 9) / NTILE) % NKCX;
    int dir = (e >> 9) / (NTILE * NKCX);
    int k = kc * 32 + ((lane >> 4) * 8) + j;
    int col = tile * 16 + (lane & 15);
    const float* W = dir ? Wxb : Wxf;
    float v = (k < ND && col < C3H) ? W[k * C3H + col] : 0.f;
    wxp[e] = (f16)v;
  } else if (e < NX + NHW) {
    int e2 = e - NX;
    int j = e2 & 7, lane = (e2 >> 3) & 63;
    int tile = (e2 >> 9) % NTILE;
    int kc = ((e2 >> 9) / NTILE) % NKCH;
    int dir = (e2 >> 9) / (NTILE * NKCH);
    int k = kc * 32 + ((lane >> 4) * 8) + j;
    int col = tile * 16 + (lane & 15);
    const float* W = dir ? Whb : Whf;
    float v = (k < NH && col < C3H) ? W[k * C3H + col] : 0.f;
    whp[e2] = (f16)v;
  }
}

// ---------------------------------------------------------------------------
// xp[dir][t][b][608] = f16( x(_rev) @ Wx + bx + [bh_z|bh_r|0] )
// (bh z/r parts folded into xp: z=sigm(xz+rz) is additive; bh_h cannot fold.)
// Block: 512 thr (8 waves), BM=128 rows (one t, half of b), wave owns 5 col
// tiles x all 8 row-tiles. A (x rows, f16) staged once in LDS; B fragments
// staged per k-chunk via global_load_lds dwordx4.
// ---------------------------------------------------------------------------
__global__ __launch_bounds__(512, 2) void xproj(
    const float* __restrict__ x, const int* __restrict__ len,
    const f16* __restrict__ wxp,
    const float* __restrict__ bxf, const float* __restrict__ bxb,
    const float* __restrict__ bhf, const float* __restrict__ bhb,
    f16* __restrict__ xp) {
  __shared__ f16 As[128 * 328];   // stride 328 f16 = 656 B (2-way bank aliasing: free)
  __shared__ f16 Bs[NTILE * 512];
  int blk = blockIdx.x;
  int dir = blk >> 9;
  int m0 = (blk & 511) * 128;
  int t = m0 >> 8;
  int bstart = m0 & 255;
  int tid = threadIdx.x;
  int lane = tid & 63, w = tid >> 6;

  { // stage A: 128 rows x 300 fp32 -> f16, pad K to 320 with zeros
    int r = tid >> 2, q = tid & 3;
    int b = bstart + r;
    int srct = t;
    if (dir) { int L = len[b]; srct = L - 1 - t; if (srct < 0) srct = 0; }
    const float* xrow = x + ((size_t)b * NT + srct) * ND;
#pragma unroll
    for (int s = 0; s < 20; ++s) {
      int i4 = q + 4 * s;                 // float4 index < 80 (75 real)
      f16x4 h4;
      if (i4 < 75) {
        float4 v = *(const float4*)(xrow + 4 * i4);
        h4 = (f16x4){(f16)v.x, (f16)v.y, (f16)v.z, (f16)v.w};
      } else {
        h4 = (f16x4){(f16)0.f, (f16)0.f, (f16)0.f, (f16)0.f};
      }
      *(f16x4*)(&As[r * 328 + 4 * i4]) = h4;
    }
  }

  f32x4 acc[8][5];
#pragma unroll
  for (int rt = 0; rt < 8; ++rt)
#pragma unroll
    for (int i = 0; i < 5; ++i) acc[rt][i] = (f32x4){0.f, 0.f, 0.f, 0.f};

  const f16* wxp_d = wxp + (size_t)dir * NKCX * NTILE * 512;
  for (int kc = 0; kc < NKCX; ++kc) {
#pragma unroll
    for (int i = 0; i < 5; ++i) {        // wave-op copies exactly one tile (1024 B)
      int idx = w + 8 * i;
      const f16* src = wxp_d + ((size_t)kc * NTILE + idx) * 512 + lane * 8;
      __builtin_amdgcn_global_load_lds((ga_u32*)src, (lds_u32*)(&Bs[idx * 512]), 16, 0, 0);
    }
    __syncthreads();
#pragma unroll
    for (int rt = 0; rt < 8; ++rt) {
      f16x8 af = *(const f16x8*)(&As[(rt * 16 + (lane & 15)) * 328 + kc * 32 + (lane >> 4) * 8]);
#pragma unroll
      for (int i = 0; i < 5; ++i) {
        f16x8 bf = *(const f16x8*)(&Bs[(5 * w + i) * 512 + lane * 8]);
        acc[rt][i] = __builtin_amdgcn_mfma_f32_16x16x32_f16(af, bf, acc[rt][i], 0, 0, 0);
      }
    }
    __syncthreads();
  }

  const float* bx = dir ? bxb : bxf;
  const float* bh = dir ? bhb : bhf;
  int g = lane >> 4, c = lane & 15;
#pragma unroll
  for (int i = 0; i < 5; ++i) {
    int tile = 5 * w + i;
    int col = tile * 16 + c;
    if (col < C3H) {
      float addv = bx[col] + (col < 2 * NH ? bh[col] : 0.f);
#pragma unroll
      for (int rt = 0; rt < 8; ++rt) {
        int row0 = rt * 16 + g * 4;
        size_t base = (((size_t)dir * NT + t) * NB + bstart + row0) * XPC + col;
#pragma unroll
        for (int jj = 0; jj < 4; ++jj)
          xp[base + (size_t)jj * XPC] = (f16)(acc[rt][i][jj] + addv);
      }
    }
  }
}

// ---------------------------------------------------------------------------
// Persistent bidirectional GRU scan. 32 blocks = 2 dirs x 16 groups of 16
// batch rows; rows are independent -> no inter-block sync. 8 waves; Wh held
// in VGPRs (7 kc x 5 tiles x f16x8 per wave). h (f16) in LDS [16][232],
// rec in LDS [16][648]. Gate phase: 400 threads, each owns (row, 8 j's).
// ---------------------------------------------------------------------------
__global__ __launch_bounds__(512, 2) void birnn(
    const f16* __restrict__ xp, const f16* __restrict__ whp,
    const int* __restrict__ len,
    const float* __restrict__ bhf, const float* __restrict__ bhb,
    float* __restrict__ sums) {
  __shared__ f16 hls[16 * 232];
  __shared__ f16 recls[16 * 648];
  int blk = blockIdx.x;
  int dir = blk >> 4;
  int b0 = (blk & 15) << 4;
  int tid = threadIdx.x;
  int lane = tid & 63, w = tid >> 6;

  f16x8 wh[NKCH][5];
  const f16* whp_d = whp + (size_t)dir * NKCH * NTILE * 512;
#pragma unroll
  for (int kc = 0; kc < NKCH; ++kc)
#pragma unroll
    for (int i = 0; i < 5; ++i)
      wh[kc][i] = *(const f16x8*)(whp_d + ((size_t)kc * NTILE + 5 * w + i) * 512 + lane * 8);

  for (int o = tid; o < 16 * 232; o += 512) hls[o] = (f16)0.f;  // h0 = 0, K-pad stays 0

  int gr = tid / 25, gq = tid - gr * 25;   // gate thread: row gr, cols 8*gq..8*gq+7
  bool gact = tid < 400;
  int lenr = 0;
  float bhh8[8];
  float sum8[8] = {0.f,0.f,0.f,0.f,0.f,0.f,0.f,0.f};
  const float* bh = dir ? bhb : bhf;
  if (gact) {
    lenr = len[b0 + gr];
#pragma unroll
    for (int e = 0; e < 8; ++e) bhh8[e] = bh[2 * NH + 8 * gq + e];
  }
  int maxlen = 0;
  for (int i = 0; i < 16; ++i) { int L = len[b0 + i]; maxlen = L > maxlen ? L : maxlen; }
  __syncthreads();

  int g = lane >> 4, c = lane & 15;
  for (int t = 0; t < NT; ++t) {
    if (t >= maxlen) break;              // uniform across block
    f16x8 xz, xr, xh;
    if (gact) {                          // prefetch xp[t] early (hides HBM under MFMA)
      const f16* xprow = xp + (((size_t)dir * NT + t) * NB + b0 + gr) * XPC + 8 * gq;
      xz = *(const f16x8*)(xprow);
      xr = *(const f16x8*)(xprow + 200);
      xh = *(const f16x8*)(xprow + 400);
    }
    // rec = h @ Wh  (A from LDS h, B resident in VGPRs)
    f32x4 acc[5];
    {
      f16x8 af = *(const f16x8*)(&hls[c * 232 + g * 8]);
#pragma unroll
      for (int i = 0; i < 5; ++i)
        acc[i] = __builtin_amdgcn_mfma_f32_16x16x32_f16(af, wh[0][i], (f32x4){0.f,0.f,0.f,0.f}, 0, 0, 0);
#pragma unroll
      for (int kc = 1; kc < NKCH; ++kc) {
        f16x8 a2 = *(const f16x8*)(&hls[c * 232 + kc * 32 + g * 8]);
#pragma unroll
        for (int i = 0; i < 5; ++i)
          acc[i] = __builtin_amdgcn_mfma_f32_16x16x32_f16(a2, wh[kc][i], acc[i], 0, 0, 0);
      }
    }
#pragma unroll
    for (int i = 0; i < 5; ++i) {        // D layout: row=(lane>>4)*4+jj, col=tile*16+(lane&15)
      int col = (5 * w + i) * 16 + c;
#pragma unroll
      for (int jj = 0; jj < 4; ++jj)
        recls[(g * 4 + jj) * 648 + col] = (f16)acc[i][jj];
    }
    __syncthreads();
    if (gact && t < lenr) {              // per-thread skip after sequence end
      const f16* rrow = &recls[gr * 648 + 8 * gq];
      f16x8 rz = *(const f16x8*)(rrow);
      f16x8 rr = *(const f16x8*)(rrow + 200);
      f16x8 rh = *(const f16x8*)(rrow + 400);
      f16x8 hold = *(const f16x8*)(&hls[gr * 232 + 8 * gq]);
      f16x8 hnew;
#pragma unroll
      for (int e = 0; e < 8; ++e) {
        float z  = sigm((float)xz[e] + (float)rz[e]);           // bh_z folded into xp
        float rg = sigm((float)xr[e] + (float)rr[e]);           // bh_r folded into xp
        float hh = tanh_f((float)xh[e] + rg * ((float)rh[e] + bhh8[e]));
        float hn = z * (float)hold[e] + (1.f - z) * hh;
        sum8[e] += hn;
        hnew[e] = (f16)hn;
      }
      *(f16x8*)(&hls[gr * 232 + 8 * gq]) = hnew;
    }
    __syncthreads();
  }
  if (gact) {
    float* o = sums + ((size_t)dir * NB + b0 + gr) * NH + 8 * gq;
#pragma unroll
    for (int e = 0; e < 8; ++e) o[e] = sum8[e];
  }
}

// ---------------------------------------------------------------------------
// out[b][o] = tanh( (concat(sum_f,sum_b)/L^2) @ Wd + bd )
// ---------------------------------------------------------------------------
__global__ void head_k(const float* __restrict__ sums, const int* __restrict__ len,
                       const float* __restrict__ Wd, const float* __restrict__ bd,
                       float* __restrict__ out) {
  __shared__ float pl[2 * NH];
  int b = blockIdx.x, tid = threadIdx.x;
  float L = (float)len[b];
  float inv = 1.f / (L * L);
  for (int k = tid; k < 2 * NH; k += 128) {
    int d = k < NH ? 0 : 1;
    int j = k < NH ? k : k - NH;
    pl[k] = sums[((size_t)d * NB + b) * NH + j] * inv;
  }
  __syncthreads();
  if (tid < NOUT) {
    float a = bd[tid];
    for (int k = 0; k < 2 * NH; ++k) a = fmaf(pl[k], Wd[k * NOUT + tid], a);
    out[b * NOUT + tid] = tanhf(a);
  }
}

extern "C" void kernel_launch(void* const* d_in, const int* in_sizes, int n_in,
                              void* d_out, int out_size, void* d_ws, size_t ws_size,
                              hipStream_t stream) {
  const float* x   = (const float*)d_in[0];
  const int*   len = (const int*)d_in[1];
  const float* Wxf = (const float*)d_in[2];
  const float* Whf = (const float*)d_in[3];
  const float* bxf = (const float*)d_in[4];
  const float* bhf = (const float*)d_in[5];
  const float* Wxb = (const float*)d_in[6];
  const float* Whb = (const float*)d_in[7];
  const float* bxb = (const float*)d_in[8];
  const float* bhb = (const float*)d_in[9];
  const float* Wd  = (const float*)d_in[10];
  const float* bd  = (const float*)d_in[11];
  float* out = (float*)d_out;
  char* ws = (char*)d_ws;
  f16* xp  = (f16*)(ws);
  f16* wxp = (f16*)(ws + XP_BYTES);
  f16* whp = (f16*)(ws + XP_BYTES + WXP_BYTES);
  float* sums = (float*)(ws + XP_BYTES + WXP_BYTES + WHP_BYTES);

  hipLaunchKernelGGL(pack_w, dim3(2720), dim3(256), 0, stream,
                     Wxf, Wxb, Whf, Whb, wxp, whp);
  hipLaunchKernelGGL(xproj, dim3(1024), dim3(512), 0, stream,
                     x, len, wxp, bxf, bxb, bhf, bhb, xp);
  hipLaunchKernelGGL(birnn, dim3(32), dim3(512), 0, stream,
                     xp, whp, len, bhf, bhb, sums);
  hipLaunchKernelGGL(head_k, dim3(256), dim3(128), 0, stream,
                     sums, len, Wd, bd, out);
}

// Round 2
// 881.715 us; speedup vs baseline: 1.2323x; 1.2323x over previous
//
#include <hip/hip_runtime.h>
#include <hip/hip_fp16.h>
#include <stdint.h>

typedef _Float16 f16;
typedef _Float16 f16x8 __attribute__((ext_vector_type(8)));
typedef _Float16 f16x4 __attribute__((ext_vector_type(4)));
typedef float f32x4 __attribute__((ext_vector_type(4)));
typedef uint32_t u32x4 __attribute__((ext_vector_type(4)));

#define NB 256
#define NT 256
#define ND 300
#define NH 200
#define NOUT 100
#define C3H 600
#define NTILE 40          // xproj B tiles (39 real sectioned tiles + 1 dummy)
#define NKCX 10           // K=300 -> 320 = 10 chunks of 32
#define NKCH 7            // K=200 -> 224 = 7 chunks of 32
#define WHT 48            // whp tile space: 16 triples x 3 sections
#define SLABF 9984        // f16 per (dir,t,bg) xp slab: 39 chunks x 64 lanes x 4
#define SLABB 19968       // bytes per slab

#define XP_BYTES   (2ull * NT * 16 * SLABB)          // 163,577,856
#define WXP_BYTES  (2ull * NKCX * NTILE * 512 * 2)   // 819,200
#define WHP_BYTES  (2ull * NKCH * WHT * 512 * 2)     // 688,128

typedef const __attribute__((address_space(1))) uint32_t ga_u32;
typedef __attribute__((address_space(3))) uint32_t lds_u32;

__device__ __forceinline__ float sigm(float x) {
  // graceful at extremes: exp->inf -> 0, exp->0 -> 1
  return 1.f / (1.f + __expf(-x));
}
__device__ __forceinline__ float tanh_f(float x) {
  x = fminf(fmaxf(x, -15.f), 15.f);
  float e = __expf(2.f * x);
  return (e - 1.f) / (e + 1.f);
}

// ---------------------------------------------------------------------------
// Column space is "sectioned": logical col600 = s*200 + (ii*16 + c), where
// s in {z,r,h}, triple ii in 0..12 (13 tiles of 16 cover 208 >= 200), c 0..15.
// This makes z/r/h for one h-column live in tiles exactly 13 apart, so one
// MFMA lane's D fragments for (ii, s=0,1,2) cover a full gate computation.
// pack_w emits per-lane MFMA B-fragment streams; k = kc*32+(lane>>4)*8+j.
// ---------------------------------------------------------------------------
__global__ void pack_w(const float* __restrict__ Wxf, const float* __restrict__ Wxb,
                       const float* __restrict__ Whf, const float* __restrict__ Whb,
                       f16* __restrict__ wxp, f16* __restrict__ whp) {
  int e = blockIdx.x * 256 + threadIdx.x;
  const int NX = 2 * NKCX * NTILE * 512;     // 409,600
  const int NHW = 2 * NKCH * WHT * 512;      // 344,064
  if (e < NX) {
    int j = e & 7, lane = (e >> 3) & 63;
    int tile = (e >> 9) % NTILE;
    int kc = ((e >> 9) / NTILE) % NKCX;
    int dir = (e >> 9) / (NTILE * NKCX);
    int k = kc * 32 + ((lane >> 4) * 8) + j;
    int c = lane & 15;
    float v = 0.f;
    if (tile < 39) {
      int s = tile / 13, ii = tile % 13;
      int hc = ii * 16 + c;
      if (k < ND && hc < NH) {
        const float* W = dir ? Wxb : Wxf;
        v = W[k * C3H + s * NH + hc];
      }
    }
    wxp[e] = (f16)v;
  } else if (e < NX + NHW) {
    int e2 = e - NX;
    int j = e2 & 7, lane = (e2 >> 3) & 63;
    int tile = (e2 >> 9) % WHT;
    int kc = ((e2 >> 9) / WHT) % NKCH;
    int dir = (e2 >> 9) / (WHT * NKCH);
    int tp = tile / 3, s = tile % 3;
    int k = kc * 32 + ((lane >> 4) * 8) + j;
    int c = lane & 15;
    float v = 0.f;
    if (tp < 13) {
      int hc = tp * 16 + c;
      if (k < NH && hc < NH) {
        const float* W = dir ? Whb : Whf;
        v = W[k * C3H + s * NH + hc];
      }
    }
    whp[e2] = (f16)v;
  }
}

// ---------------------------------------------------------------------------
// xproj: xp_c[dir][t][bg][chunk(39)][lane(64)][jj(4)] f16 =
//   x(_rev) @ Wx + bx + [bh_z|bh_r|0]   (bh z/r fold; bh_h applied in gate)
// chunk = ii*3 + s; element is row (bg*16 + (lane>>4)*4 + jj), hcol ii*16+(lane&15).
// This is exactly the MFMA C-fragment layout birnn's gate lanes consume, so
// birnn staging is a linear 20KB copy via global_load_lds.
// ---------------------------------------------------------------------------
__global__ __launch_bounds__(512, 2) void xproj(
    const float* __restrict__ x, const int* __restrict__ len,
    const f16* __restrict__ wxp,
    const float* __restrict__ bxf, const float* __restrict__ bxb,
    const float* __restrict__ bhf, const float* __restrict__ bhb,
    f16* __restrict__ xp) {
  __shared__ f16 As[128 * 328];
  __shared__ f16 Bs[NTILE * 512];
  int blk = blockIdx.x;
  int dir = blk >> 9;
  int m0 = (blk & 511) * 128;
  int t = m0 >> 8;
  int bstart = m0 & 255;
  int tid = threadIdx.x;
  int lane = tid & 63, w = tid >> 6;

  { // stage A: 128 rows x 300 fp32 -> f16, K padded to 320 with zeros
    int r = tid >> 2, q = tid & 3;
    int b = bstart + r;
    int srct = t;
    if (dir) { int L = len[b]; srct = L - 1 - t; if (srct < 0) srct = 0; }
    const float* xrow = x + ((size_t)b * NT + srct) * ND;
#pragma unroll
    for (int s = 0; s < 20; ++s) {
      int i4 = q + 4 * s;
      f16x4 h4;
      if (i4 < 75) {
        float4 v = *(const float4*)(xrow + 4 * i4);
        h4 = (f16x4){(f16)v.x, (f16)v.y, (f16)v.z, (f16)v.w};
      } else {
        h4 = (f16x4){(f16)0.f, (f16)0.f, (f16)0.f, (f16)0.f};
      }
      *(f16x4*)(&As[r * 328 + 4 * i4]) = h4;
    }
  }

  f32x4 acc[8][5];
#pragma unroll
  for (int rt = 0; rt < 8; ++rt)
#pragma unroll
    for (int i = 0; i < 5; ++i) acc[rt][i] = (f32x4){0.f, 0.f, 0.f, 0.f};

  const f16* wxp_d = wxp + (size_t)dir * NKCX * NTILE * 512;
  for (int kc = 0; kc < NKCX; ++kc) {
#pragma unroll
    for (int i = 0; i < 5; ++i) {
      int idx = w + 8 * i;
      const f16* src = wxp_d + ((size_t)kc * NTILE + idx) * 512 + lane * 8;
      __builtin_amdgcn_global_load_lds((ga_u32*)src, (lds_u32*)(&Bs[idx * 512]), 16, 0, 0);
    }
    __syncthreads();
#pragma unroll
    for (int rt = 0; rt < 8; ++rt) {
      f16x8 af = *(const f16x8*)(&As[(rt * 16 + (lane & 15)) * 328 + kc * 32 + (lane >> 4) * 8]);
#pragma unroll
      for (int i = 0; i < 5; ++i) {
        f16x8 bf = *(const f16x8*)(&Bs[(5 * w + i) * 512 + lane * 8]);
        acc[rt][i] = __builtin_amdgcn_mfma_f32_16x16x32_f16(af, bf, acc[rt][i], 0, 0, 0);
      }
    }
    __syncthreads();
  }

  const float* bx = dir ? bxb : bxf;
  const float* bh = dir ? bhb : bhf;
  int c = lane & 15;
#pragma unroll
  for (int i = 0; i < 5; ++i) {
    int tile = 5 * w + i;
    if (tile >= 39) continue;
    int s = tile / 13, ii = tile % 13;
    int hc = ii * 16 + c;
    float addv = 0.f;
    if (hc < NH) {
      int col600 = s * NH + hc;
      addv = bx[col600] + (s < 2 ? bh[col600] : 0.f);
    }
#pragma unroll
    for (int rt = 0; rt < 8; ++rt) {
      int bg = (bstart >> 4) + rt;
      f16* dst = xp + (((size_t)dir * NT + t) * 16 + bg) * SLABF + ((ii * 3 + s) * 64 + lane) * 4;
      f16x4 v4 = {(f16)(acc[rt][i][0] + addv), (f16)(acc[rt][i][1] + addv),
                  (f16)(acc[rt][i][2] + addv), (f16)(acc[rt][i][3] + addv)};
      *(f16x4*)dst = v4;
    }
  }
}

// ---------------------------------------------------------------------------
// Persistent bidirectional GRU. 32 blocks = 2 dirs x 16 groups of 16 rows.
// 8 waves; wave w owns triples {w, w+8} (triples >=13 are zero-padded dummies).
// Wh fragments pinned in VGPRs via opaque-asm (42 x u32x4 busiest wave).
// Per step: 1 barrier; h double-buffered in LDS (MFMA A-side only); gate fully
// in registers (z/r/h accs are the lane's own D fragments); h_old/sums in regs.
// Waves 5-7 additionally stage xp[t+1] into LDS double-buffer (global_load_lds).
// ---------------------------------------------------------------------------
__global__ __launch_bounds__(512, 2) void birnn(
    const f16* __restrict__ xp, const f16* __restrict__ whp,
    const int* __restrict__ len,
    const float* __restrict__ bhf, const float* __restrict__ bhb,
    float* __restrict__ sums) {
  __shared__ f16 hls[2][16 * 232];
  __shared__ __align__(16) f16 xpl[2][10240];   // 20480 B each (20 x 1024B ops)
  int blk = blockIdx.x;
  int dir = blk >> 4;
  int b0 = (blk & 15) << 4;
  int tid = threadIdx.x;
  int lane = tid & 63, w = tid >> 6;
  int g = lane >> 4, c = lane & 15;

  // ---- load Wh fragments and pin in VGPRs ----
  u32x4 whu[2][3][7];
  const f16* whp_d = whp + (size_t)dir * NKCH * WHT * 512;
#pragma unroll
  for (int tp = 0; tp < 2; ++tp) {
    int trip = tp ? (w + 8) : w;
#pragma unroll
    for (int s = 0; s < 3; ++s)
#pragma unroll
      for (int kc = 0; kc < NKCH; ++kc)
        whu[tp][s][kc] = *(const u32x4*)(whp_d + ((size_t)(kc * WHT + trip * 3 + s)) * 512 + lane * 8);
  }
#pragma unroll
  for (int tp = 0; tp < 2; ++tp)
#pragma unroll
    for (int s = 0; s < 3; ++s)
#pragma unroll
      for (int kc = 0; kc < NKCH; ++kc)
        asm volatile("" : "+v"(whu[tp][s][kc]));   // opaque: cannot rematerialize

  for (int o = tid; o < 2 * 16 * 232; o += 512) ((f16*)hls)[o] = (f16)0.f;

  int len4[4];
#pragma unroll
  for (int jj = 0; jj < 4; ++jj) len4[jj] = len[b0 + g * 4 + jj];
  int maxlen = 0;
  for (int i = 0; i < 16; ++i) { int L = len[b0 + i]; maxlen = L > maxlen ? L : maxlen; }

  const float* bh = dir ? bhb : bhf;
  float bhh[2] = {0.f, 0.f};
  f16x4 hreg[2] = {(f16x4){(f16)0.f,(f16)0.f,(f16)0.f,(f16)0.f},
                   (f16x4){(f16)0.f,(f16)0.f,(f16)0.f,(f16)0.f}};
  f32x4 sum[2] = {(f32x4){0.f,0.f,0.f,0.f}, (f32x4){0.f,0.f,0.f,0.f}};
#pragma unroll
  for (int tp = 0; tp < 2; ++tp) {
    int ii = tp ? (w + 8) : w;
    int hc = ii * 16 + c;
    if (ii < 13 && hc < NH) bhh[tp] = bh[2 * NH + hc];
  }

  const char* slab0 = (const char*)(xp) + (((size_t)dir * NT) * 16 + (b0 >> 4)) * (size_t)SLABB;
  const size_t slab_stride = (size_t)16 * SLABB;   // per t

  // prologue: stage xp[0]
  if (w >= 5) {
    int o0 = (w - 5) * 7, o1 = (w == 7) ? 20 : o0 + 7;
    const char* src = slab0;
    for (int k = o0; k < o1; ++k)
      __builtin_amdgcn_global_load_lds((ga_u32*)(src + k * 1024 + lane * 16),
                                       (lds_u32*)((char*)(&xpl[0][0]) + k * 1024), 16, 0, 0);
  }
  __syncthreads();

  for (int t = 0; t < maxlen; ++t) {
    int cur = t & 1, nxt = cur ^ 1;
    // issue next slab early: latency hides under this step's MFMA+gate
    if (w >= 5 && (t + 1) < maxlen) {
      int o0 = (w - 5) * 7, o1 = (w == 7) ? 20 : o0 + 7;
      const char* src = slab0 + (size_t)(t + 1) * slab_stride;
      for (int k = o0; k < o1; ++k)
        __builtin_amdgcn_global_load_lds((ga_u32*)(src + k * 1024 + lane * 16),
                                         (lds_u32*)((char*)(&xpl[nxt][0]) + k * 1024), 16, 0, 0);
    }

    // rec = h @ Wh : A from LDS h fragments, B resident in VGPRs
    f32x4 acc[2][3];
#pragma unroll
    for (int tp = 0; tp < 2; ++tp)
#pragma unroll
      for (int s = 0; s < 3; ++s) acc[tp][s] = (f32x4){0.f, 0.f, 0.f, 0.f};
#pragma unroll
    for (int kc = 0; kc < NKCH; ++kc) {
      f16x8 a = *(const f16x8*)(&hls[cur][c * 232 + kc * 32 + g * 8]);
#pragma unroll
      for (int tp = 0; tp < 2; ++tp)
#pragma unroll
        for (int s = 0; s < 3; ++s)
          acc[tp][s] = __builtin_amdgcn_mfma_f32_16x16x32_f16(
              a, __builtin_bit_cast(f16x8, whu[tp][s][kc]), acc[tp][s], 0, 0, 0);
    }

    // gate: everything in registers (acc z/r/h + xp fragment + h_old + sums)
#pragma unroll
    for (int tp = 0; tp < 2; ++tp) {
      int ii = tp ? (w + 8) : w;
      if (ii < 13) {
        f16x4 xz4 = *(const f16x4*)(&xpl[cur][((ii * 3 + 0) * 64 + lane) * 4]);
        f16x4 xr4 = *(const f16x4*)(&xpl[cur][((ii * 3 + 1) * 64 + lane) * 4]);
        f16x4 xh4 = *(const f16x4*)(&xpl[cur][((ii * 3 + 2) * 64 + lane) * 4]);
#pragma unroll
        for (int jj = 0; jj < 4; ++jj) {
          float z = sigm((float)xz4[jj] + acc[tp][0][jj]);
          float r = sigm((float)xr4[jj] + acc[tp][1][jj]);
          float hh = tanh_f((float)xh4[jj] + r * (acc[tp][2][jj] + bhh[tp]));
          float hold = (float)hreg[tp][jj];
          float hn = z * hold + (1.f - z) * hh;
          bool va = (t < len4[jj]);
          hn = va ? hn : hold;
          hreg[tp][jj] = (f16)hn;
          sum[tp][jj] += va ? hn : 0.f;
        }
        int hc = ii * 16 + c;
        if (hc < NH) {
#pragma unroll
          for (int jj = 0; jj < 4; ++jj)
            hls[nxt][(g * 4 + jj) * 232 + hc] = hreg[tp][jj];
        }
      }
    }
    __syncthreads();   // drains staging vmcnt (needed) + LDS writes
  }

#pragma unroll
  for (int tp = 0; tp < 2; ++tp) {
    int ii = tp ? (w + 8) : w;
    int hc = ii * 16 + c;
    if (ii < 13 && hc < NH) {
#pragma unroll
      for (int jj = 0; jj < 4; ++jj)
        sums[((size_t)dir * NB + b0 + g * 4 + jj) * NH + hc] = sum[tp][jj];
    }
  }
}

// ---------------------------------------------------------------------------
// out[b][o] = tanh( (concat(sum_f,sum_b)/L^2) @ Wd + bd )
// ---------------------------------------------------------------------------
__global__ void head_k(const float* __restrict__ sums, const int* __restrict__ len,
                       const float* __restrict__ Wd, const float* __restrict__ bd,
                       float* __restrict__ out) {
  __shared__ float pl[2 * NH];
  int b = blockIdx.x, tid = threadIdx.x;
  float L = (float)len[b];
  float inv = 1.f / (L * L);
  for (int k = tid; k < 2 * NH; k += 128) {
    int d = k < NH ? 0 : 1;
    int j = k < NH ? k : k - NH;
    pl[k] = sums[((size_t)d * NB + b) * NH + j] * inv;
  }
  __syncthreads();
  if (tid < NOUT) {
    float a = bd[tid];
    for (int k = 0; k < 2 * NH; ++k) a = fmaf(pl[k], Wd[k * NOUT + tid], a);
    out[b * NOUT + tid] = tanhf(a);
  }
}

extern "C" void kernel_launch(void* const* d_in, const int* in_sizes, int n_in,
                              void* d_out, int out_size, void* d_ws, size_t ws_size,
                              hipStream_t stream) {
  const float* x   = (const float*)d_in[0];
  const int*   len = (const int*)d_in[1];
  const float* Wxf = (const float*)d_in[2];
  const float* Whf = (const float*)d_in[3];
  const float* bxf = (const float*)d_in[4];
  const float* bhf = (const float*)d_in[5];
  const float* Wxb = (const float*)d_in[6];
  const float* Whb = (const float*)d_in[7];
  const float* bxb = (const float*)d_in[8];
  const float* bhb = (const float*)d_in[9];
  const float* Wd  = (const float*)d_in[10];
  const float* bd  = (const float*)d_in[11];
  float* out = (float*)d_out;
  char* ws = (char*)d_ws;
  f16* xp  = (f16*)(ws);
  f16* wxp = (f16*)(ws + XP_BYTES + 1024);           // 1KB pad: staging overread
  f16* whp = (f16*)(ws + XP_BYTES + 1024 + WXP_BYTES);
  float* sums = (float*)(ws + XP_BYTES + 1024 + WXP_BYTES + WHP_BYTES);

  hipLaunchKernelGGL(pack_w, dim3(2944), dim3(256), 0, stream,
                     Wxf, Wxb, Whf, Whb, wxp, whp);
  hipLaunchKernelGGL(xproj, dim3(1024), dim3(512), 0, stream,
                     x, len, wxp, bxf, bxb, bhf, bhb, xp);
  hipLaunchKernelGGL(birnn, dim3(32), dim3(512), 0, stream,
                     xp, whp, len, bhf, bhb, sums);
  hipLaunchKernelGGL(head_k, dim3(256), dim3(128), 0, stream,
                     sums, len, Wd, bd, out);
}

// Round 5
// 623.768 us; speedup vs baseline: 1.7419x; 1.4135x over previous
//
#include <hip/hip_runtime.h>
#include <hip/hip_fp16.h>
#include <stdint.h>

typedef _Float16 f16;
typedef _Float16 f16x8 __attribute__((ext_vector_type(8)));
typedef _Float16 f16x4 __attribute__((ext_vector_type(4)));
typedef _Float16 f16x2 __attribute__((ext_vector_type(2)));
typedef float f32x4 __attribute__((ext_vector_type(4)));
typedef uint32_t u32x4 __attribute__((ext_vector_type(4)));

#define NB 256
#define NT 256
#define ND 300
#define NH 200
#define NOUT 100
#define C3H 600
#define NTILE 40          // xproj B tiles (39 real sectioned tiles + 1 dummy)
#define NKCX 10           // K=300 -> 320 = 10 chunks of 32
#define NKCH 7            // K=200 -> 224 = 7 chunks of 32
#define WHT 48            // whp tile space: 16 triples x 3 sections
#define SLABF 9984        // f16 per (dir,t,bg) xp slab: 39 chunks x 64 lanes x 4
#define SLABB 19968       // bytes per slab
#define LOG2E 1.44269504088896f

#define XP_BYTES   (2ull * NT * 16 * SLABB)          // 163,577,856
#define WXP_BYTES  (2ull * NKCX * NTILE * 512 * 2)   // 819,200
#define WHP_BYTES  (2ull * NKCH * WHT * 512 * 2)     // 688,128

typedef const __attribute__((address_space(1))) uint32_t ga_u32;
typedef __attribute__((address_space(3))) uint32_t lds_u32;

__device__ __forceinline__ float fast_exp2(float x) {
#if __has_builtin(__builtin_amdgcn_exp2f)
  return __builtin_amdgcn_exp2f(x);
#else
  return exp2f(x);
#endif
}
__device__ __forceinline__ float fast_rcp(float x) {
#if __has_builtin(__builtin_amdgcn_rcpf)
  return __builtin_amdgcn_rcpf(x);
#else
  return 1.f / x;
#endif
}

// ---------------------------------------------------------------------------
// Sectioned column space: col600 = s*200 + (ii*16 + c); z/r/h for one h-col
// live in tiles 13 apart so one lane's D fragments cover a full gate.
// exp2 pre-scaling baked into the packed weights:
//   s=0 (z), s=1 (r): x -log2e      -> sigmoid(a) = rcp(1 + exp2(scaled))
//   s=2 (h):          x 2*log2e     -> tanh(c)    = 1 - 2*rcp(1 + exp2(scaled))
// ---------------------------------------------------------------------------
__global__ void pack_w(const float* __restrict__ Wxf, const float* __restrict__ Wxb,
                       const float* __restrict__ Whf, const float* __restrict__ Whb,
                       f16* __restrict__ wxp, f16* __restrict__ whp) {
  int e = blockIdx.x * 256 + threadIdx.x;
  const int NX = 2 * NKCX * NTILE * 512;     // 409,600
  const int NHW = 2 * NKCH * WHT * 512;      // 344,064
  if (e < NX) {
    int j = e & 7, lane = (e >> 3) & 63;
    int tile = (e >> 9) % NTILE;
    int kc = ((e >> 9) / NTILE) % NKCX;
    int dir = (e >> 9) / (NTILE * NKCX);
    int k = kc * 32 + ((lane >> 4) * 8) + j;
    int c = lane & 15;
    float v = 0.f;
    if (tile < 39) {
      int s = tile / 13, ii = tile % 13;
      int hc = ii * 16 + c;
      if (k < ND && hc < NH) {
        const float* W = dir ? Wxb : Wxf;
        float sc = (s == 2) ? 2.f * LOG2E : -LOG2E;
        v = W[k * C3H + s * NH + hc] * sc;
      }
    }
    wxp[e] = (f16)v;
  } else if (e < NX + NHW) {
    int e2 = e - NX;
    int j = e2 & 7, lane = (e2 >> 3) & 63;
    int tile = (e2 >> 9) % WHT;
    int kc = ((e2 >> 9) / WHT) % NKCH;
    int dir = (e2 >> 9) / (WHT * NKCH);
    int tp = tile / 3, s = tile % 3;
    int k = kc * 32 + ((lane >> 4) * 8) + j;
    int c = lane & 15;
    float v = 0.f;
    if (tp < 13) {
      int hc = tp * 16 + c;
      if (k < NH && hc < NH) {
        const float* W = dir ? Whb : Whf;
        float sc = (s == 2) ? 2.f * LOG2E : -LOG2E;
        v = W[k * C3H + s * NH + hc] * sc;
      }
    }
    whp[e2] = (f16)v;
  }
}

// ---------------------------------------------------------------------------
// xproj: xp_c[dir][t][bg][chunk(39)][lane(64)][jj(4)] f16 =
//   scale_s * ( x(_rev) @ Wx + bx + [bh_z|bh_r|0] )   (scale baked in wxp/addv)
// Layout = exactly the MFMA C-fragment layout birnn's gate lanes consume.
// ---------------------------------------------------------------------------
__global__ __launch_bounds__(512, 2) void xproj(
    const float* __restrict__ x, const int* __restrict__ len,
    const f16* __restrict__ wxp,
    const float* __restrict__ bxf, const float* __restrict__ bxb,
    const float* __restrict__ bhf, const float* __restrict__ bhb,
    f16* __restrict__ xp) {
  __shared__ f16 As[128 * 328];
  __shared__ f16 Bs[NTILE * 512];
  int blk = blockIdx.x;
  int dir = blk >> 9;
  int m0 = (blk & 511) * 128;
  int t = m0 >> 8;
  int bstart = m0 & 255;
  int tid = threadIdx.x;
  int lane = tid & 63, w = tid >> 6;

  { // stage A: 128 rows x 300 fp32 -> f16, K padded to 320 with zeros
    int r = tid >> 2, q = tid & 3;
    int b = bstart + r;
    int srct = t;
    if (dir) { int L = len[b]; srct = L - 1 - t; if (srct < 0) srct = 0; }
    const float* xrow = x + ((size_t)b * NT + srct) * ND;
#pragma unroll
    for (int s = 0; s < 20; ++s) {
      int i4 = q + 4 * s;
      f16x4 h4;
      if (i4 < 75) {
        float4 v = *(const float4*)(xrow + 4 * i4);
        h4 = (f16x4){(f16)v.x, (f16)v.y, (f16)v.z, (f16)v.w};
      } else {
        h4 = (f16x4){(f16)0.f, (f16)0.f, (f16)0.f, (f16)0.f};
      }
      *(f16x4*)(&As[r * 328 + 4 * i4]) = h4;
    }
  }

  f32x4 acc[8][5];
#pragma unroll
  for (int rt = 0; rt < 8; ++rt)
#pragma unroll
    for (int i = 0; i < 5; ++i) acc[rt][i] = (f32x4){0.f, 0.f, 0.f, 0.f};

  const f16* wxp_d = wxp + (size_t)dir * NKCX * NTILE * 512;
  for (int kc = 0; kc < NKCX; ++kc) {
#pragma unroll
    for (int i = 0; i < 5; ++i) {
      int idx = w + 8 * i;
      const f16* src = wxp_d + ((size_t)kc * NTILE + idx) * 512 + lane * 8;
      __builtin_amdgcn_global_load_lds((ga_u32*)src, (lds_u32*)(&Bs[idx * 512]), 16, 0, 0);
    }
    __syncthreads();
#pragma unroll
    for (int rt = 0; rt < 8; ++rt) {
      f16x8 af = *(const f16x8*)(&As[(rt * 16 + (lane & 15)) * 328 + kc * 32 + (lane >> 4) * 8]);
#pragma unroll
      for (int i = 0; i < 5; ++i) {
        f16x8 bf = *(const f16x8*)(&Bs[(5 * w + i) * 512 + lane * 8]);
        acc[rt][i] = __builtin_amdgcn_mfma_f32_16x16x32_f16(af, bf, acc[rt][i], 0, 0, 0);
      }
    }
    __syncthreads();
  }

  const float* bx = dir ? bxb : bxf;
  const float* bh = dir ? bhb : bhf;
  int c = lane & 15;
#pragma unroll
  for (int i = 0; i < 5; ++i) {
    int tile = 5 * w + i;
    if (tile >= 39) continue;
    int s = tile / 13, ii = tile % 13;
    int hc = ii * 16 + c;
    float addv = 0.f;
    if (hc < NH) {
      int col600 = s * NH + hc;
      float sc = (s == 2) ? 2.f * LOG2E : -LOG2E;
      addv = (bx[col600] + (s < 2 ? bh[col600] : 0.f)) * sc;
    }
#pragma unroll
    for (int rt = 0; rt < 8; ++rt) {
      int bg = (bstart >> 4) + rt;
      f16* dst = xp + (((size_t)dir * NT + t) * 16 + bg) * SLABF + ((ii * 3 + s) * 64 + lane) * 4;
      f16x4 v4 = {(f16)(acc[rt][i][0] + addv), (f16)(acc[rt][i][1] + addv),
                  (f16)(acc[rt][i][2] + addv), (f16)(acc[rt][i][3] + addv)};
      *(f16x4*)dst = v4;
    }
  }
}

// ---------------------------------------------------------------------------
// Persistent bidirectional GRU. 32 blocks = 2 dirs x 16 groups of 16 rows.
// 8 waves; wave w owns triples {w, w+8}. Wh fragments pinned in VGPRs
// (168 VGPR) -- amdgpu_waves_per_eu(2,2) pins the allocator's occupancy
// target to 2 waves/SIMD = 256 VGPR budget so they are NOT spilled (R2's
// failure: default heuristic targeted 4 waves/EU = 128 VGPR and spilled).
// Gates: exp2/rcp pre-scaled forms, no clamps, h_old in f32 registers.
// ---------------------------------------------------------------------------
__global__ __launch_bounds__(512)
__attribute__((amdgpu_waves_per_eu(2, 2)))
void birnn(
    const f16* __restrict__ xp, const f16* __restrict__ whp,
    const int* __restrict__ len,
    const float* __restrict__ bhf, const float* __restrict__ bhb,
    float* __restrict__ sums) {
  __shared__ f16 hls[2][16 * 232];
  __shared__ __align__(16) f16 xpl[2][10240];   // 20480 B each (20 x 1024B ops)
  int blk = blockIdx.x;
  int dir = blk >> 4;
  int b0 = (blk & 15) << 4;
  int tid = threadIdx.x;
  int lane = tid & 63, w = tid >> 6;
  int g = lane >> 4, c = lane & 15;

  // ---- load Wh fragments and pin in VGPRs ----
  u32x4 whu[2][3][7];
  const f16* whp_d = whp + (size_t)dir * NKCH * WHT * 512;
#pragma unroll
  for (int tp = 0; tp < 2; ++tp) {
    int trip = tp ? (w + 8) : w;
#pragma unroll
    for (int s = 0; s < 3; ++s)
#pragma unroll
      for (int kc = 0; kc < NKCH; ++kc)
        whu[tp][s][kc] = *(const u32x4*)(whp_d + ((size_t)(kc * WHT + trip * 3 + s)) * 512 + lane * 8);
  }
#pragma unroll
  for (int tp = 0; tp < 2; ++tp)
#pragma unroll
    for (int s = 0; s < 3; ++s)
#pragma unroll
      for (int kc = 0; kc < NKCH; ++kc)
        asm volatile("" : "+v"(whu[tp][s][kc]));   // opaque: cannot rematerialize

  for (int o = tid; o < 2 * 16 * 232; o += 512) ((f16*)hls)[o] = (f16)0.f;

  int len4[4];
#pragma unroll
  for (int jj = 0; jj < 4; ++jj) len4[jj] = len[b0 + g * 4 + jj];
  int maxlen = 0;
  for (int i = 0; i < 16; ++i) { int L = len[b0 + i]; maxlen = L > maxlen ? L : maxlen; }

  const float* bh = dir ? bhb : bhf;
  float bhh[2] = {0.f, 0.f};           // pre-scaled by 2*log2e
  f32x4 hreg[2] = {(f32x4){0.f,0.f,0.f,0.f}, (f32x4){0.f,0.f,0.f,0.f}};
  f32x4 sum[2] = {(f32x4){0.f,0.f,0.f,0.f}, (f32x4){0.f,0.f,0.f,0.f}};
#pragma unroll
  for (int tp = 0; tp < 2; ++tp) {
    int ii = tp ? (w + 8) : w;
    int hc = ii * 16 + c;
    if (ii < 13 && hc < NH) bhh[tp] = bh[2 * NH + hc] * (2.f * LOG2E);
  }

  const char* slab0 = (const char*)(xp) + (((size_t)dir * NT) * 16 + (b0 >> 4)) * (size_t)SLABB;
  const size_t slab_stride = (size_t)16 * SLABB;   // per t

  // prologue: stage xp[0]
  if (w >= 5) {
    int o0 = (w - 5) * 7, o1 = (w == 7) ? 20 : o0 + 7;
    const char* src = slab0;
    for (int k = o0; k < o1; ++k)
      __builtin_amdgcn_global_load_lds((ga_u32*)(src + k * 1024 + lane * 16),
                                       (lds_u32*)((char*)(&xpl[0][0]) + k * 1024), 16, 0, 0);
  }
  __syncthreads();

  for (int t = 0; t < maxlen; ++t) {
    int cur = t & 1, nxt = cur ^ 1;
    // issue next slab early: latency hides under this step's MFMA+gate
    if (w >= 5 && (t + 1) < maxlen) {
      int o0 = (w - 5) * 7, o1 = (w == 7) ? 20 : o0 + 7;
      const char* src = slab0 + (size_t)(t + 1) * slab_stride;
      for (int k = o0; k < o1; ++k)
        __builtin_amdgcn_global_load_lds((ga_u32*)(src + k * 1024 + lane * 16),
                                         (lds_u32*)((char*)(&xpl[nxt][0]) + k * 1024), 16, 0, 0);
    }

    // rec = h @ Wh : A from LDS h fragments, B resident in VGPRs
    f32x4 acc[2][3];
#pragma unroll
    for (int tp = 0; tp < 2; ++tp)
#pragma unroll
      for (int s = 0; s < 3; ++s) acc[tp][s] = (f32x4){0.f, 0.f, 0.f, 0.f};
#pragma unroll
    for (int kc = 0; kc < NKCH; ++kc) {
      f16x8 a = *(const f16x8*)(&hls[cur][c * 232 + kc * 32 + g * 8]);
#pragma unroll
      for (int tp = 0; tp < 2; ++tp)
#pragma unroll
        for (int s = 0; s < 3; ++s)
          acc[tp][s] = __builtin_amdgcn_mfma_f32_16x16x32_f16(
              a, __builtin_bit_cast(f16x8, whu[tp][s][kc]), acc[tp][s], 0, 0, 0);
    }

    // gate: all-register; sigmoid = rcp(1+exp2(.)), tanh = 1-2*rcp(1+exp2(.))
#pragma unroll
    for (int tp = 0; tp < 2; ++tp) {
      int ii = tp ? (w + 8) : w;
      if (ii < 13) {
        f16x4 xz4 = *(const f16x4*)(&xpl[cur][((ii * 3 + 0) * 64 + lane) * 4]);
        f16x4 xr4 = *(const f16x4*)(&xpl[cur][((ii * 3 + 1) * 64 + lane) * 4]);
        f16x4 xh4 = *(const f16x4*)(&xpl[cur][((ii * 3 + 2) * 64 + lane) * 4]);
#pragma unroll
        for (int jj = 0; jj < 4; ++jj) {
          float az = (float)xz4[jj] + acc[tp][0][jj];
          float z  = fast_rcp(1.f + fast_exp2(az));
          float ar = (float)xr4[jj] + acc[tp][1][jj];
          float r  = fast_rcp(1.f + fast_exp2(ar));
          float c2 = fmaf(r, acc[tp][2][jj] + bhh[tp], (float)xh4[jj]);
          float q2 = fast_rcp(1.f + fast_exp2(c2));
          float th = fmaf(-2.f, q2, 1.f);
          float hold = hreg[tp][jj];
          float hn = fmaf(z, hold - th, th);
          bool va = (t < len4[jj]);
          hn = va ? hn : hold;
          hreg[tp][jj] = hn;
          sum[tp][jj] += va ? hn : 0.f;
        }
        int hc = ii * 16 + c;
        if (hc < NH) {
          f16x2 plo = __builtin_bit_cast(f16x2, __builtin_amdgcn_cvt_pkrtz(hreg[tp][0], hreg[tp][1]));
          f16x2 phi = __builtin_bit_cast(f16x2, __builtin_amdgcn_cvt_pkrtz(hreg[tp][2], hreg[tp][3]));
          hls[nxt][(g * 4 + 0) * 232 + hc] = plo[0];
          hls[nxt][(g * 4 + 1) * 232 + hc] = plo[1];
          hls[nxt][(g * 4 + 2) * 232 + hc] = phi[0];
          hls[nxt][(g * 4 + 3) * 232 + hc] = phi[1];
        }
      }
    }
    __syncthreads();   // drains staging vmcnt (needed) + LDS writes
  }

#pragma unroll
  for (int tp = 0; tp < 2; ++tp) {
    int ii = tp ? (w + 8) : w;
    int hc = ii * 16 + c;
    if (ii < 13 && hc < NH) {
#pragma unroll
      for (int jj = 0; jj < 4; ++jj)
        sums[((size_t)dir * NB + b0 + g * 4 + jj) * NH + hc] = sum[tp][jj];
    }
  }
}

// ---------------------------------------------------------------------------
// out[b][o] = tanh( (concat(sum_f,sum_b)/L^2) @ Wd + bd )
// ---------------------------------------------------------------------------
__global__ void head_k(const float* __restrict__ sums, const int* __restrict__ len,
                       const float* __restrict__ Wd, const float* __restrict__ bd,
                       float* __restrict__ out) {
  __shared__ float pl[2 * NH];
  int b = blockIdx.x, tid = threadIdx.x;
  float L = (float)len[b];
  float inv = 1.f / (L * L);
  for (int k = tid; k < 2 * NH; k += 128) {
    int d = k < NH ? 0 : 1;
    int j = k < NH ? k : k - NH;
    pl[k] = sums[((size_t)d * NB + b) * NH + j] * inv;
  }
  __syncthreads();
  if (tid < NOUT) {
    float a = bd[tid];
    for (int k = 0; k < 2 * NH; ++k) a = fmaf(pl[k], Wd[k * NOUT + tid], a);
    out[b * NOUT + tid] = tanhf(a);
  }
}

extern "C" void kernel_launch(void* const* d_in, const int* in_sizes, int n_in,
                              void* d_out, int out_size, void* d_ws, size_t ws_size,
                              hipStream_t stream) {
  const float* x   = (const float*)d_in[0];
  const int*   len = (const int*)d_in[1];
  const float* Wxf = (const float*)d_in[2];
  const float* Whf = (const float*)d_in[3];
  const float* bxf = (const float*)d_in[4];
  const float* bhf = (const float*)d_in[5];
  const float* Wxb = (const float*)d_in[6];
  const float* Whb = (const float*)d_in[7];
  const float* bxb = (const float*)d_in[8];
  const float* bhb = (const float*)d_in[9];
  const float* Wd  = (const float*)d_in[10];
  const float* bd  = (const float*)d_in[11];
  float* out = (float*)d_out;
  char* ws = (char*)d_ws;
  f16* xp  = (f16*)(ws);
  f16* wxp = (f16*)(ws + XP_BYTES + 1024);           // 1KB pad: staging overread
  f16* whp = (f16*)(ws + XP_BYTES + 1024 + WXP_BYTES);
  float* sums = (float*)(ws + XP_BYTES + 1024 + WXP_BYTES + WHP_BYTES);

  hipLaunchKernelGGL(pack_w, dim3(2944), dim3(256), 0, stream,
                     Wxf, Wxb, Whf, Whb, wxp, whp);
  hipLaunchKernelGGL(xproj, dim3(1024), dim3(512), 0, stream,
                     x, len, wxp, bxf, bxb, bhf, bhb, xp);
  hipLaunchKernelGGL(birnn, dim3(32), dim3(512), 0, stream,
                     xp, whp, len, bhf, bhb, sums);
  hipLaunchKernelGGL(head_k, dim3(256), dim3(128), 0, stream,
                     sums, len, Wd, bd, out);
}